// Round 8
// baseline (1056.289 us; speedup 1.0000x reference)
//
#include <hip/hip_runtime.h>
#include <hip/hip_bf16.h>
#include <cstdint>

#define B_ 256
#define F_ 128
#define D_ 512
#define H_ 8
#define KVAL_ 64

typedef unsigned short ushort_t;
typedef __attribute__((ext_vector_type(8))) short short8;
typedef __attribute__((ext_vector_type(4))) float floatx4;
typedef __attribute__((ext_vector_type(2))) float floatx2;
typedef __attribute__((ext_vector_type(2))) double doublex2;

__device__ __forceinline__ unsigned f2ord32(float f) {
  unsigned b = __float_as_uint(f);
  return (b & 0x80000000u) ? ~b : (b | 0x80000000u);
}

__device__ __forceinline__ unsigned long long f2ord64(double s) {
  unsigned long long b = (unsigned long long)__double_as_longlong(s);
  return (b & 0x8000000000000000ull) ? ~b : (b | 0x8000000000000000ull);
}

__device__ __forceinline__ ushort_t f2bf(float f) {
  __hip_bfloat16 h = __float2bfloat16(f);
  return *reinterpret_cast<ushort_t*>(&h);
}
__device__ __forceinline__ float bf2f(ushort_t u) {
  __hip_bfloat16 h = *reinterpret_cast<__hip_bfloat16*>(&u);
  return __bfloat162float(h);
}

// ---------------------------------------------------------------------------
// pv gate in fp64 (selection-critical): means -> silu MLP -> sigmoid.
// ---------------------------------------------------------------------------
__global__ __launch_bounds__(256) void pv_kernel(
    const float* __restrict__ x, const float* __restrict__ W1,
    const float* __restrict__ b1, const float* __restrict__ W2,
    const float* __restrict__ b2, double* __restrict__ pv) {
  __shared__ double comb[1024];
  __shared__ double red[4];
  int b = blockIdx.x, t = threadIdx.x;
  {
    const float* xb = x + (size_t)b * (F_ * D_) + 2 * t;
    double p0 = 0.0, p1 = 0.0, v0 = 0.0, v1 = 0.0;
#pragma unroll 8
    for (int f = 0; f < 64; ++f) {
      floatx2 xp = *(const floatx2*)(xb + (size_t)f * D_);
      floatx2 xv = *(const floatx2*)(xb + (size_t)(f + 64) * D_);
      p0 += (double)xp[0];
      p1 += (double)xp[1];
      v0 += (double)xv[0];
      v1 += (double)xv[1];
    }
    comb[2 * t] = p0 * (1.0 / 64.0);
    comb[2 * t + 1] = p1 * (1.0 / 64.0);
    comb[512 + 2 * t] = v0 * (1.0 / 64.0);
    comb[512 + 2 * t + 1] = v1 * (1.0 / 64.0);
  }
  __syncthreads();
  double a0 = (double)b1[2 * t], a1 = (double)b1[2 * t + 1];
  const float* wp = W1 + 2 * t;
#pragma unroll 8
  for (int k = 0; k < 1024; ++k) {
    double c = comb[k];
    floatx2 wv = *(const floatx2*)(wp + (size_t)k * 512);
    a0 += c * (double)wv[0];
    a1 += c * (double)wv[1];
  }
  double h0 = a0 / (1.0 + exp(-a0));  // silu
  double h1 = a1 / (1.0 + exp(-a1));
  double part = h0 * (double)W2[2 * t] + h1 * (double)W2[2 * t + 1];
  for (int off = 32; off; off >>= 1) part += __shfl_xor(part, off);
  int lane = t & 63, w = t >> 6;
  if (lane == 0) red[w] = part;
  __syncthreads();
  if (t == 0) {
    double tot = red[0] + red[1] + red[2] + red[3] + (double)b2[0];
    pv[b] = 1.0 / (1.0 + exp(-tot));
  }
}

// ---------------------------------------------------------------------------
// pack [Wq|Wk] -> transposed [n=1024][k=512] 3-term bf16 split (h/m/l) +
// fp64 bqk
// ---------------------------------------------------------------------------
__global__ __launch_bounds__(256) void pack_wqk3_kernel(
    const float* __restrict__ Wq, const float* __restrict__ Wk,
    const float* __restrict__ bq, const float* __restrict__ bk,
    ushort_t* __restrict__ Wh, ushort_t* __restrict__ Wm,
    ushort_t* __restrict__ Wl, double* __restrict__ bqk) {
  int idx = blockIdx.x * 256 + threadIdx.x;  // 0 .. 1024*512-1
  int n = idx >> 9, k = idx & 511;
  float v = (n < 512) ? Wq[(size_t)k * 512 + n] : Wk[(size_t)k * 512 + (n - 512)];
  ushort_t h = f2bf(v);
  float r1 = v - bf2f(h);
  ushort_t m = f2bf(r1);
  ushort_t l = f2bf(r1 - bf2f(m));
  Wh[idx] = h;
  Wm[idx] = m;
  Wl[idx] = l;
  if (idx < 1024)
    bqk[idx] = (double)((idx < 512) ? bq[idx] : bk[idx - 512]);
}

// ---------------------------------------------------------------------------
// pack W (512x512 fp32, [k][n]) -> WT hi/lo bf16 [n][k] split (value path)
// ---------------------------------------------------------------------------
__global__ __launch_bounds__(256) void pack_wt_kernel(
    const float* __restrict__ W, ushort_t* __restrict__ hiT,
    ushort_t* __restrict__ loT) {
  int i = blockIdx.x * 256 + threadIdx.x;
  int n = i >> 9, k = i & 511;
  float v = W[(size_t)k * 512 + n];
  ushort_t h = f2bf(v);
  hiT[i] = h;
  loT[i] = f2bf(v - bf2f(h));
}

// ---------------------------------------------------------------------------
// per-chunk x -> 3-term bf16 split (h/m/l), row-major [m][k=512].
// ---------------------------------------------------------------------------
__global__ __launch_bounds__(256) void xsplit3_kernel(
    const float* __restrict__ x, ushort_t* __restrict__ xh,
    ushort_t* __restrict__ xm, ushort_t* __restrict__ xl) {
  int i = blockIdx.x * 256 + threadIdx.x;  // oct index
  const float* xp = x + (size_t)i * 8;
  floatx4 f0 = *(const floatx4*)xp;
  floatx4 f1 = *(const floatx4*)(xp + 4);
  short8 vh, vm, vl;
#pragma unroll
  for (int j = 0; j < 8; ++j) {
    float fv = (j < 4) ? f0[j] : f1[j - 4];
    ushort_t hb = f2bf(fv);
    float r1 = fv - bf2f(hb);
    ushort_t mb = f2bf(r1);
    ushort_t lb = f2bf(r1 - bf2f(mb));
    vh[j] = (short)hb;
    vm[j] = (short)mb;
    vl[j] = (short)lb;
  }
  *(short8*)&xh[(size_t)i * 8] = vh;
  *(short8*)&xm[(size_t)i * 8] = vm;
  *(short8*)&xl[(size_t)i * 8] = vl;
}

// ---------------------------------------------------------------------------
// q/k projection v4: C[M,1024](f32) = A[M,512] @ Wqk + bqk via 6-segment
// split-bf16 MFMA. f32 C is bit-identical to the f64 path (biases zero).
// XCD-chunked swizzle.
// ---------------------------------------------------------------------------
__global__ __launch_bounds__(256) void mfma_qk_v3(
    const ushort_t* __restrict__ Xh, const ushort_t* __restrict__ Xm,
    const ushort_t* __restrict__ Xl, const ushort_t* __restrict__ Wh,
    const ushort_t* __restrict__ Wm, const ushort_t* __restrict__ Wl,
    const double* __restrict__ bias, float* __restrict__ C, int nb) {
  __shared__ ushort_t As[3][128 * 40];
  __shared__ ushort_t Bs[3][128 * 40];
  int s = blockIdx.x;
  int o = (s & 7) * nb + (s >> 3);  // bijective: nwg = 8*nb
  int n0 = (o & 7) * 128, m0 = (o >> 3) * 128;
  int t = threadIdx.x;
  int lane = t & 63, w = t >> 6;
  int wm_ = w >> 1, wn = w & 1;
  int mrow = lane & 15, quad = lane >> 4;
  floatx4 acc[4][4] = {};
  for (int kp = 0; kp < 16; ++kp) {
    int k0 = kp * 32;
    __syncthreads();
#pragma unroll
    for (int p = 0; p < 2; ++p) {
      int idx = p * 256 + t;
      int r = idx >> 2, c = (idx & 3) * 8;
      size_t aoff = (size_t)(m0 + r) * 512 + k0 + c;
      *(short8*)&As[0][r * 40 + c] = *(const short8*)(Xh + aoff);
      *(short8*)&As[1][r * 40 + c] = *(const short8*)(Xm + aoff);
      *(short8*)&As[2][r * 40 + c] = *(const short8*)(Xl + aoff);
      size_t boff = (size_t)(n0 + r) * 512 + k0 + c;
      *(short8*)&Bs[0][r * 40 + c] = *(const short8*)(Wh + boff);
      *(short8*)&Bs[1][r * 40 + c] = *(const short8*)(Wm + boff);
      *(short8*)&Bs[2][r * 40 + c] = *(const short8*)(Wl + boff);
    }
    __syncthreads();
#pragma unroll
    for (int sa = 0; sa < 3; ++sa) {
      short8 af[4];
#pragma unroll
      for (int mt = 0; mt < 4; ++mt)
        af[mt] = *(const short8*)&As[sa][(wm_ * 64 + mt * 16 + mrow) * 40 + quad * 8];
#pragma unroll
      for (int sb = 0; sb < 3; ++sb) {
        if (sa + sb > 2) continue;
        short8 bf[4];
#pragma unroll
        for (int nt = 0; nt < 4; ++nt)
          bf[nt] = *(const short8*)&Bs[sb][(wn * 64 + nt * 16 + mrow) * 40 + quad * 8];
#pragma unroll
        for (int mt = 0; mt < 4; ++mt)
#pragma unroll
          for (int nt = 0; nt < 4; ++nt)
            acc[mt][nt] = __builtin_amdgcn_mfma_f32_16x16x32_bf16(
                af[mt], bf[nt], acc[mt][nt], 0, 0, 0);
      }
    }
  }
#pragma unroll
  for (int nt = 0; nt < 4; ++nt) {
    int gn = n0 + wn * 64 + nt * 16 + mrow;
    double bb = bias[gn];
#pragma unroll
    for (int mt = 0; mt < 4; ++mt) {
      int gm = m0 + wm_ * 64 + mt * 16 + quad * 4;
#pragma unroll
      for (int rg = 0; rg < 4; ++rg)
        C[(size_t)(gm + rg) * 1024 + gn] = (float)((double)acc[mt][nt][rg] + bb);
    }
  }
}

// ---------------------------------------------------------------------------
// value-path split-bf16 MFMA GEMM v2 (verified round 4): fused k-sweep +
// XCD-chunked swizzle.
// ---------------------------------------------------------------------------
__global__ __launch_bounds__(256) void mfma_gemm_split(
    const float* __restrict__ A, const ushort_t* __restrict__ WhiT,
    const ushort_t* __restrict__ WloT, const float* __restrict__ bias,
    float* __restrict__ C) {
  __shared__ ushort_t Ah[128 * 40];
  __shared__ ushort_t Al[128 * 40];
  __shared__ ushort_t Bh[128 * 40];
  __shared__ ushort_t Bl[128 * 40];
  int s = blockIdx.x;
  int o = (s & 7) * 128 + (s >> 3);  // nwg = 1024, cpx = 128
  int n0 = (o & 3) * 128, m0 = (o >> 2) * 128;
  int t = threadIdx.x;
  int lane = t & 63, w = t >> 6;
  int wm = w >> 1, wn = w & 1;
  int mrow = lane & 15, quad = lane >> 4;
  floatx4 acc[4][4] = {};
  for (int kp = 0; kp < 16; ++kp) {
    int k0 = kp * 32;
    __syncthreads();
#pragma unroll
    for (int p = 0; p < 2; ++p) {
      int idx = p * 256 + t;
      int r = idx >> 2, c = (idx & 3) * 8;
      const float* ap = A + (size_t)(m0 + r) * 512 + k0 + c;
      floatx4 f0 = *(const floatx4*)ap;
      floatx4 f1 = *(const floatx4*)(ap + 4);
      short8 vh, vl;
#pragma unroll
      for (int j = 0; j < 8; ++j) {
        float fv = (j < 4) ? f0[j] : f1[j - 4];
        ushort_t hb = f2bf(fv);
        vh[j] = (short)hb;
        vl[j] = (short)f2bf(fv - bf2f(hb));
      }
      *(short8*)&Ah[r * 40 + c] = vh;
      *(short8*)&Al[r * 40 + c] = vl;
      size_t boff = (size_t)(n0 + r) * 512 + k0 + c;
      *(short8*)&Bh[r * 40 + c] = *(const short8*)(WhiT + boff);
      *(short8*)&Bl[r * 40 + c] = *(const short8*)(WloT + boff);
    }
    __syncthreads();
    int abase = (wm * 64 + mrow) * 40 + quad * 8;
    int bbase = (wn * 64 + mrow) * 40 + quad * 8;
    short8 ah[4], bh[4];
#pragma unroll
    for (int i = 0; i < 4; ++i) {
      ah[i] = *(const short8*)&Ah[abase + i * 640];
      bh[i] = *(const short8*)&Bh[bbase + i * 640];
    }
#pragma unroll
    for (int mt = 0; mt < 4; ++mt)
#pragma unroll
      for (int nt = 0; nt < 4; ++nt)
        acc[mt][nt] = __builtin_amdgcn_mfma_f32_16x16x32_bf16(
            ah[mt], bh[nt], acc[mt][nt], 0, 0, 0);
    {
      short8 al[4];
#pragma unroll
      for (int i = 0; i < 4; ++i) al[i] = *(const short8*)&Al[abase + i * 640];
#pragma unroll
      for (int mt = 0; mt < 4; ++mt)
#pragma unroll
        for (int nt = 0; nt < 4; ++nt)
          acc[mt][nt] = __builtin_amdgcn_mfma_f32_16x16x32_bf16(
              al[mt], bh[nt], acc[mt][nt], 0, 0, 0);
    }
    {
      short8 bl[4];
#pragma unroll
      for (int i = 0; i < 4; ++i) bl[i] = *(const short8*)&Bl[bbase + i * 640];
#pragma unroll
      for (int mt = 0; mt < 4; ++mt)
#pragma unroll
        for (int nt = 0; nt < 4; ++nt)
          acc[mt][nt] = __builtin_amdgcn_mfma_f32_16x16x32_bf16(
              ah[mt], bl[nt], acc[mt][nt], 0, 0, 0);
    }
  }
#pragma unroll
  for (int nt = 0; nt < 4; ++nt) {
    int gn = n0 + wn * 64 + nt * 16 + mrow;
    float bb = bias[gn];
#pragma unroll
    for (int mt = 0; mt < 4; ++mt) {
      int gm = m0 + wm * 64 + mt * 16 + quad * 4;
#pragma unroll
      for (int rg = 0; rg < 4; ++rg)
        C[(size_t)(gm + rg) * 512 + gn] = acc[mt][nt][rg] + bb;
    }
  }
}

// ---------------------------------------------------------------------------
// attention v8: identical per-row math to verified v7 (f32 qk, fp64 score
// dot via cvt, f32-radix select + exact u64 refine, EPS=2e-6 ramp, 64KB LDS
// pool reuse). Latency restructure, VGPR-neutral (target <=64 for 32
// waves/CU):
//  - barrier moved up to end of d-loop (kT/q reads done) -> p-region free
//    before select
//  - p written to LDS inline in the select loop (drops p0s/p1s reg arrays,
//    -16 VGPR)
//  - 8-deep v prefetch ISSUED BEFORE the select phase (T14: ~3k cy of
//    select hides the v latency); consumed in strict ascending-j order
//    (bit-identical accumulation)
//  - pp reads widened to ds_read_b128 broadcasts
// ---------------------------------------------------------------------------
__global__ __launch_bounds__(1024) void attn_kernel(
    const float* __restrict__ qk, const float* __restrict__ vbuf,
    const float* __restrict__ corr_prior, const float* __restrict__ feat_imp,
    const double* __restrict__ pv, float* __restrict__ attn_out, int b_off,
    int nb) {
  __shared__ __align__(16) float smem[16384];  // 64KB pool
  // phase A: kT = smem[0:8192) as [d=64][128 skewed]; q_w = smem[8192+w*512)
  // phase B (after barrier): p_w = smem[w*1024 .. +1024)
  int s = blockIdx.x;
  int o = (s & 7) * nb + (s >> 3);  // nwg = 8*nb
  int b = o >> 3, h = o & 7;  // chunk-local b
  int t = threadIdx.x, lane = t & 63, w = t >> 6;
#pragma unroll
  for (int n = 0; n < 8; ++n) {
    int f = w + 16 * n;
    smem[lane * 128 + ((f + lane) & 127)] =
        qk[((size_t)(b * F_ + f)) * 1024 + 512 + h * 64 + lane];
  }
  float* qpw = &smem[8192 + w * 512];
  int fb = 8 * w;  // this wave's 8-row group
#pragma unroll
  for (int i = 0; i < 8; ++i)
    qpw[i * 64 + lane] =
        qk[((size_t)(b * F_ + fb + i)) * 1024 + h * 64 + lane];
  __syncthreads();
  double pvb = pv[b_off + b] * 0.5;
  double fiA = (double)feat_imp[lane];
  double fiB = (double)feat_imp[64 + lane];
  const double SLOPE = 2.5e5;  // 1/(2*EPS), EPS = 2e-6
  double s0[8], s1[8];
#pragma unroll
  for (int i = 0; i < 8; ++i) {
    s0[i] = 0.0;
    s1[i] = 0.0;
  }
#pragma unroll 2
  for (int d = 0; d < 64; d += 2) {
    double kd0a = (double)smem[d * 128 + ((lane + d) & 127)];
    double kd1a = (double)smem[d * 128 + ((lane + 64 + d) & 127)];
    double kd0b = (double)smem[(d + 1) * 128 + ((lane + 1 + d) & 127)];
    double kd1b = (double)smem[(d + 1) * 128 + ((lane + 65 + d) & 127)];
#pragma unroll
    for (int i = 0; i < 8; ++i) {
      floatx2 q2 = *(const floatx2*)&qpw[i * 64 + d];
      double qa = (double)q2[0], qb = (double)q2[1];
      s0[i] += qa * kd0a;
      s1[i] += qa * kd1a;
      s0[i] += qb * kd0b;
      s1[i] += qb * kd1b;
    }
  }
  // kT/q reads complete for ALL waves -> pool reusable for p after barrier
  __syncthreads();
  float* pp = &smem[w * 1024];
  // issue 8-deep v prefetch now; select phase below hides the latency
  const float* vb = vbuf + ((size_t)b * F_) * 512 + h * 64 + lane;
  float vr[8];
#pragma unroll
  for (int u = 0; u < 8; ++u) vr[u] = vb[(size_t)u * 512];
#pragma unroll
  for (int i = 0; i < 8; ++i) {
    int f = fb + i;
    double sa = s0[i], sb = s1[i];
    double fif = (double)feat_imp[f];
    double cp0 = (double)corr_prior[f * 128 + lane] * fif * fiA;
    double cp1 = (double)corr_prior[f * 128 + 64 + lane] * fif * fiB;
    double add0 = (f < 64) ? 0.0 : pvb;
    double add1 = (f < 64) ? pvb : 0.0;
    sa = sa * 0.125 + cp0 + add0;
    sb = sb * 0.125 + cp1 + add1;
    // stage 1: 32-round select on f32-ordered keys (monotone cast)
    unsigned a0 = f2ord32((float)sa), a1 = f2ord32((float)sb), T = 0u;
    for (int bit = 31; bit >= 0; --bit) {
      unsigned cand = T | (1u << bit);
      int c = __popcll(__ballot(a0 >= cand)) + __popcll(__ballot(a1 >= cand));
      if (c >= KVAL_) T = cand;
    }
    int cnt_gt = __popcll(__ballot(a0 > T)) + __popcll(__ballot(a1 > T));
    int cnt_ge = __popcll(__ballot(a0 >= T)) + __popcll(__ballot(a1 >= T));
    int bsz = cnt_ge - cnt_gt;
    int r = KVAL_ - cnt_gt;  // in-bucket kept count
    double bmax = -1e300;    // max strictly below bucket
    if (a0 < T) bmax = sa;
    if (a1 < T && sb > bmax) bmax = sb;
    for (int off = 32; off; off >>= 1) bmax = fmax(bmax, __shfl_xor(bmax, off));
    double sT, sU;
    if (bsz == r) {  // common: whole bucket kept
      double tmin = 1e300;
      if (a0 == T) tmin = sa;
      if (a1 == T && sb < tmin) tmin = sb;
      for (int off = 32; off; off >>= 1) tmin = fmin(tmin, __shfl_xor(tmin, off));
      sT = tmin;
      sU = bmax;
    } else {  // rare: exact u64 refine inside tied bucket
      unsigned long long x0 = (a0 == T) ? f2ord64(sa) : 0ull;
      unsigned long long x1 = (a1 == T) ? f2ord64(sb) : 0ull;
      unsigned long long T64 = 0ull;
      for (int bit = 63; bit >= 0; --bit) {
        unsigned long long cand = T64 | (1ull << bit);
        int c = __popcll(__ballot(x0 >= cand)) + __popcll(__ballot(x1 >= cand));
        if (c >= r) T64 = cand;
      }
      double tv = -1e300, uv = bmax;
      if (x0 == T64) tv = sa;
      if (x1 == T64 && sb > tv) tv = sb;
      if (a0 == T && x0 < T64 && sa > uv) uv = sa;
      if (a1 == T && x1 < T64 && sb > uv) uv = sb;
      for (int off = 32; off; off >>= 1) {
        tv = fmax(tv, __shfl_xor(tv, off));
        uv = fmax(uv, __shfl_xor(uv, off));
      }
      sT = tv;
      sU = uv;
    }
    double mid = 0.5 * (sT + sU);
    double W0 = fmin(1.0, fmax(0.0, 0.5 + (sa - mid) * SLOPE));
    double W1v = fmin(1.0, fmax(0.0, 0.5 + (sb - mid) * SLOPE));
    double mm = fmax(sa, sb);
    for (int off = 32; off; off >>= 1) mm = fmax(mm, __shfl_xor(mm, off));
    float p0 = (float)W0 * expf((float)(sa - mm));
    float p1 = (float)W1v * expf((float)(sb - mm));
    float zz = p0 + p1;
    for (int off = 32; off; off >>= 1) zz += __shfl_xor(zz, off);
    float inv = 1.f / zz;
    // write p directly to wave-private LDS (within-wave ds order guarantees
    // the PV reads below see these; no extra barrier needed)
    pp[i * 128 + lane] = p0 * inv;
    pp[i * 128 + 64 + lane] = p1 * inv;
  }
  // PV: v loads shared across the 8 rows; 8-deep rotation, strict
  // ascending-j accumulation order (bit-identical to v7)
  float o8[8] = {0.f, 0.f, 0.f, 0.f, 0.f, 0.f, 0.f, 0.f};
  for (int j = 0; j < 128; j += 8) {
    float cur[8];
#pragma unroll
    for (int u = 0; u < 8; ++u) cur[u] = vr[u];
    if (j + 8 < 128) {
#pragma unroll
      for (int u = 0; u < 8; ++u) vr[u] = vb[(size_t)(j + 8 + u) * 512];
    }
#pragma unroll
    for (int i = 0; i < 8; ++i) {
      floatx4 pa = *(const floatx4*)&pp[i * 128 + j];
      floatx4 pb4 = *(const floatx4*)&pp[i * 128 + j + 4];
      o8[i] += pa[0] * cur[0];
      o8[i] += pa[1] * cur[1];
      o8[i] += pa[2] * cur[2];
      o8[i] += pa[3] * cur[3];
      o8[i] += pb4[0] * cur[4];
      o8[i] += pb4[1] * cur[5];
      o8[i] += pb4[2] * cur[6];
      o8[i] += pb4[3] * cur[7];
    }
  }
#pragma unroll
  for (int i = 0; i < 8; ++i)
    attn_out[((size_t)(b * F_ + fb + i)) * 512 + h * 64 + lane] = o8[i];
}

extern "C" void kernel_launch(void* const* d_in, const int* in_sizes, int n_in,
                              void* d_out, int out_size, void* d_ws,
                              size_t ws_size, hipStream_t stream) {
  const float* x = (const float*)d_in[0];
  const float* Wq = (const float*)d_in[1];
  const float* bq = (const float*)d_in[2];
  const float* Wk = (const float*)d_in[3];
  const float* bk = (const float*)d_in[4];
  const float* Wv = (const float*)d_in[5];
  const float* bv = (const float*)d_in[6];
  const float* Wo = (const float*)d_in[7];
  const float* bo = (const float*)d_in[8];
  const float* corr = (const float*)d_in[9];
  const float* fimp = (const float*)d_in[10];
  const float* W1 = (const float*)d_in[11];
  const float* b1 = (const float*)d_in[12];
  const float* W2 = (const float*)d_in[13];
  const float* b2 = (const float*)d_in[14];
  float* out = (float*)d_out;
  float* ws = (float*)d_ws;

  // workspace layout (float units)
  double* pv_hi = (double*)ws;
  double* bqk_hi = (double*)(ws + 512);
  ushort_t* WqkTh = (ushort_t*)(ws + 2560);
  ushort_t* WqkTm = (ushort_t*)(ws + 264704);
  ushort_t* WqkTl = (ushort_t*)(ws + 526848);
  ushort_t* WvhiT = (ushort_t*)(ws + 788992);
  ushort_t* WvloT = (ushort_t*)(ws + 920064);
  ushort_t* WohiT = (ushort_t*)(ws + 1051136);
  ushort_t* WoloT = (ushort_t*)(ws + 1182208);
  float* vbuf = ws + 1313280;
  float* attnb = ws + 18090496;
  float* qk = ws + 34867712;  // f32
  const size_t head = 34867712;
  size_t ws_floats = ws_size / 4;
  // per-chunk per-b: qk 131072 floats + x 3-split 49152 floats
  int Bc = 8;
  for (int cand = 256; cand >= 8; cand >>= 1)
    if (head + (size_t)cand * 180224 <= ws_floats) { Bc = cand; break; }
  ushort_t* Xh = (ushort_t*)(ws + head + (size_t)Bc * 131072);
  ushort_t* Xm = Xh + (size_t)Bc * 65536;
  ushort_t* Xl = Xm + (size_t)Bc * 65536;

  hipLaunchKernelGGL(pv_kernel, dim3(B_), dim3(256), 0, stream,
                     x, W1, b1, W2, b2, pv_hi);
  hipLaunchKernelGGL(pack_wqk3_kernel, dim3(2048), dim3(256), 0, stream,
                     Wq, Wk, bq, bk, WqkTh, WqkTm, WqkTl, bqk_hi);
  hipLaunchKernelGGL(pack_wt_kernel, dim3(1024), dim3(256), 0, stream,
                     Wv, WvhiT, WvloT);
  hipLaunchKernelGGL(pack_wt_kernel, dim3(1024), dim3(256), 0, stream,
                     Wo, WohiT, WoloT);
  // v projection: full batch, M = 32768
  hipLaunchKernelGGL(mfma_gemm_split, dim3(1024), dim3(256), 0, stream,
                     x, WvhiT, WvloT, bv, vbuf);
  // selection path, chunked over batch
  for (int b0 = 0; b0 < B_; b0 += Bc) {
    hipLaunchKernelGGL(xsplit3_kernel, dim3(Bc * 32), dim3(256), 0, stream,
                       x + (size_t)b0 * 65536, Xh, Xm, Xl);
    hipLaunchKernelGGL(mfma_qk_v3, dim3(8 * Bc), dim3(256), 0, stream,
                       Xh, Xm, Xl, WqkTh, WqkTm, WqkTl, bqk_hi, qk, Bc);
    hipLaunchKernelGGL(attn_kernel, dim3(Bc * 8), dim3(1024), 0, stream,
                       qk, vbuf + (size_t)b0 * 65536, corr, fimp, pv_hi,
                       attnb + (size_t)b0 * 65536, b0, Bc);
  }
  // output projection: full batch
  hipLaunchKernelGGL(mfma_gemm_split, dim3(1024), dim3(256), 0, stream,
                     attnb, WohiT, WoloT, bo, out);
}

// Round 9
// 993.068 us; speedup vs baseline: 1.0637x; 1.0637x over previous
//
#include <hip/hip_runtime.h>
#include <hip/hip_bf16.h>
#include <cstdint>

#define B_ 256
#define F_ 128
#define D_ 512
#define H_ 8
#define KVAL_ 64

typedef unsigned short ushort_t;
typedef __attribute__((ext_vector_type(8))) short short8;
typedef __attribute__((ext_vector_type(4))) float floatx4;
typedef __attribute__((ext_vector_type(2))) float floatx2;
typedef __attribute__((ext_vector_type(2))) double doublex2;

__device__ __forceinline__ unsigned f2ord32(float f) {
  unsigned b = __float_as_uint(f);
  return (b & 0x80000000u) ? ~b : (b | 0x80000000u);
}

__device__ __forceinline__ unsigned long long f2ord64(double s) {
  unsigned long long b = (unsigned long long)__double_as_longlong(s);
  return (b & 0x8000000000000000ull) ? ~b : (b | 0x8000000000000000ull);
}

__device__ __forceinline__ ushort_t f2bf(float f) {
  __hip_bfloat16 h = __float2bfloat16(f);
  return *reinterpret_cast<ushort_t*>(&h);
}
__device__ __forceinline__ float bf2f(ushort_t u) {
  __hip_bfloat16 h = *reinterpret_cast<__hip_bfloat16*>(&u);
  return __bfloat162float(h);
}

// ---------------------------------------------------------------------------
// pv gate in fp64 (selection-critical): means -> silu MLP -> sigmoid.
// ---------------------------------------------------------------------------
__global__ __launch_bounds__(256) void pv_kernel(
    const float* __restrict__ x, const float* __restrict__ W1,
    const float* __restrict__ b1, const float* __restrict__ W2,
    const float* __restrict__ b2, double* __restrict__ pv) {
  __shared__ double comb[1024];
  __shared__ double red[4];
  int b = blockIdx.x, t = threadIdx.x;
  {
    const float* xb = x + (size_t)b * (F_ * D_) + 2 * t;
    double p0 = 0.0, p1 = 0.0, v0 = 0.0, v1 = 0.0;
#pragma unroll 8
    for (int f = 0; f < 64; ++f) {
      floatx2 xp = *(const floatx2*)(xb + (size_t)f * D_);
      floatx2 xv = *(const floatx2*)(xb + (size_t)(f + 64) * D_);
      p0 += (double)xp[0];
      p1 += (double)xp[1];
      v0 += (double)xv[0];
      v1 += (double)xv[1];
    }
    comb[2 * t] = p0 * (1.0 / 64.0);
    comb[2 * t + 1] = p1 * (1.0 / 64.0);
    comb[512 + 2 * t] = v0 * (1.0 / 64.0);
    comb[512 + 2 * t + 1] = v1 * (1.0 / 64.0);
  }
  __syncthreads();
  double a0 = (double)b1[2 * t], a1 = (double)b1[2 * t + 1];
  const float* wp = W1 + 2 * t;
#pragma unroll 8
  for (int k = 0; k < 1024; ++k) {
    double c = comb[k];
    floatx2 wv = *(const floatx2*)(wp + (size_t)k * 512);
    a0 += c * (double)wv[0];
    a1 += c * (double)wv[1];
  }
  double h0 = a0 / (1.0 + exp(-a0));  // silu
  double h1 = a1 / (1.0 + exp(-a1));
  double part = h0 * (double)W2[2 * t] + h1 * (double)W2[2 * t + 1];
  for (int off = 32; off; off >>= 1) part += __shfl_xor(part, off);
  int lane = t & 63, w = t >> 6;
  if (lane == 0) red[w] = part;
  __syncthreads();
  if (t == 0) {
    double tot = red[0] + red[1] + red[2] + red[3] + (double)b2[0];
    pv[b] = 1.0 / (1.0 + exp(-tot));
  }
}

// ---------------------------------------------------------------------------
// pack [Wq|Wk] -> transposed [n=1024][k=512] 3-term bf16 split (h/m/l) +
// fp64 bqk
// ---------------------------------------------------------------------------
__global__ __launch_bounds__(256) void pack_wqk3_kernel(
    const float* __restrict__ Wq, const float* __restrict__ Wk,
    const float* __restrict__ bq, const float* __restrict__ bk,
    ushort_t* __restrict__ Wh, ushort_t* __restrict__ Wm,
    ushort_t* __restrict__ Wl, double* __restrict__ bqk) {
  int idx = blockIdx.x * 256 + threadIdx.x;  // 0 .. 1024*512-1
  int n = idx >> 9, k = idx & 511;
  float v = (n < 512) ? Wq[(size_t)k * 512 + n] : Wk[(size_t)k * 512 + (n - 512)];
  ushort_t h = f2bf(v);
  float r1 = v - bf2f(h);
  ushort_t m = f2bf(r1);
  ushort_t l = f2bf(r1 - bf2f(m));
  Wh[idx] = h;
  Wm[idx] = m;
  Wl[idx] = l;
  if (idx < 1024)
    bqk[idx] = (double)((idx < 512) ? bq[idx] : bk[idx - 512]);
}

// ---------------------------------------------------------------------------
// pack W (512x512 fp32, [k][n]) -> WT hi/lo bf16 [n][k] split (value path)
// ---------------------------------------------------------------------------
__global__ __launch_bounds__(256) void pack_wt_kernel(
    const float* __restrict__ W, ushort_t* __restrict__ hiT,
    ushort_t* __restrict__ loT) {
  int i = blockIdx.x * 256 + threadIdx.x;
  int n = i >> 9, k = i & 511;
  float v = W[(size_t)k * 512 + n];
  ushort_t h = f2bf(v);
  hiT[i] = h;
  loT[i] = f2bf(v - bf2f(h));
}

// ---------------------------------------------------------------------------
// per-chunk x -> 3-term bf16 split (h/m/l), row-major [m][k=512].
// ---------------------------------------------------------------------------
__global__ __launch_bounds__(256) void xsplit3_kernel(
    const float* __restrict__ x, ushort_t* __restrict__ xh,
    ushort_t* __restrict__ xm, ushort_t* __restrict__ xl) {
  int i = blockIdx.x * 256 + threadIdx.x;  // oct index
  const float* xp = x + (size_t)i * 8;
  floatx4 f0 = *(const floatx4*)xp;
  floatx4 f1 = *(const floatx4*)(xp + 4);
  short8 vh, vm, vl;
#pragma unroll
  for (int j = 0; j < 8; ++j) {
    float fv = (j < 4) ? f0[j] : f1[j - 4];
    ushort_t hb = f2bf(fv);
    float r1 = fv - bf2f(hb);
    ushort_t mb = f2bf(r1);
    ushort_t lb = f2bf(r1 - bf2f(mb));
    vh[j] = (short)hb;
    vm[j] = (short)mb;
    vl[j] = (short)lb;
  }
  *(short8*)&xh[(size_t)i * 8] = vh;
  *(short8*)&xm[(size_t)i * 8] = vm;
  *(short8*)&xl[(size_t)i * 8] = vl;
}

// ---------------------------------------------------------------------------
// q/k projection v5: C[M,1024](f32) = A[M,512] @ Wqk + bqk via 6-segment
// split-bf16 MFMA. DS-read fix vs v4: all fragments pre-loaded once per
// K-tile (af[3][4] + bf[3][4] = 24 ds_read_b128, was 36 -- bf was re-read
// per (sa,sb) pair). MFMA (sa,sb) iteration order UNCHANGED -> bit-identical
// accumulation. VGPR grows (~190) but occupancy is LDS-capped at 2
// blocks/CU (60KB) either way. XCD-chunked swizzle.
// ---------------------------------------------------------------------------
__global__ __launch_bounds__(256) void mfma_qk_v3(
    const ushort_t* __restrict__ Xh, const ushort_t* __restrict__ Xm,
    const ushort_t* __restrict__ Xl, const ushort_t* __restrict__ Wh,
    const ushort_t* __restrict__ Wm, const ushort_t* __restrict__ Wl,
    const double* __restrict__ bias, float* __restrict__ C, int nb) {
  __shared__ ushort_t As[3][128 * 40];
  __shared__ ushort_t Bs[3][128 * 40];
  int s = blockIdx.x;
  int o = (s & 7) * nb + (s >> 3);  // bijective: nwg = 8*nb
  int n0 = (o & 7) * 128, m0 = (o >> 3) * 128;
  int t = threadIdx.x;
  int lane = t & 63, w = t >> 6;
  int wm_ = w >> 1, wn = w & 1;
  int mrow = lane & 15, quad = lane >> 4;
  floatx4 acc[4][4] = {};
  for (int kp = 0; kp < 16; ++kp) {
    int k0 = kp * 32;
    __syncthreads();
#pragma unroll
    for (int p = 0; p < 2; ++p) {
      int idx = p * 256 + t;
      int r = idx >> 2, c = (idx & 3) * 8;
      size_t aoff = (size_t)(m0 + r) * 512 + k0 + c;
      *(short8*)&As[0][r * 40 + c] = *(const short8*)(Xh + aoff);
      *(short8*)&As[1][r * 40 + c] = *(const short8*)(Xm + aoff);
      *(short8*)&As[2][r * 40 + c] = *(const short8*)(Xl + aoff);
      size_t boff = (size_t)(n0 + r) * 512 + k0 + c;
      *(short8*)&Bs[0][r * 40 + c] = *(const short8*)(Wh + boff);
      *(short8*)&Bs[1][r * 40 + c] = *(const short8*)(Wm + boff);
      *(short8*)&Bs[2][r * 40 + c] = *(const short8*)(Wl + boff);
    }
    __syncthreads();
    short8 af[3][4], bf[3][4];
#pragma unroll
    for (int sa = 0; sa < 3; ++sa)
#pragma unroll
      for (int mt = 0; mt < 4; ++mt)
        af[sa][mt] =
            *(const short8*)&As[sa][(wm_ * 64 + mt * 16 + mrow) * 40 + quad * 8];
#pragma unroll
    for (int sb = 0; sb < 3; ++sb)
#pragma unroll
      for (int nt = 0; nt < 4; ++nt)
        bf[sb][nt] =
            *(const short8*)&Bs[sb][(wn * 64 + nt * 16 + mrow) * 40 + quad * 8];
#pragma unroll
    for (int sa = 0; sa < 3; ++sa)
#pragma unroll
      for (int sb = 0; sb < 3; ++sb) {
        if (sa + sb > 2) continue;
#pragma unroll
        for (int mt = 0; mt < 4; ++mt)
#pragma unroll
          for (int nt = 0; nt < 4; ++nt)
            acc[mt][nt] = __builtin_amdgcn_mfma_f32_16x16x32_bf16(
                af[sa][mt], bf[sb][nt], acc[mt][nt], 0, 0, 0);
      }
  }
#pragma unroll
  for (int nt = 0; nt < 4; ++nt) {
    int gn = n0 + wn * 64 + nt * 16 + mrow;
    double bb = bias[gn];
#pragma unroll
    for (int mt = 0; mt < 4; ++mt) {
      int gm = m0 + wm_ * 64 + mt * 16 + quad * 4;
#pragma unroll
      for (int rg = 0; rg < 4; ++rg)
        C[(size_t)(gm + rg) * 1024 + gn] = (float)((double)acc[mt][nt][rg] + bb);
    }
  }
}

// ---------------------------------------------------------------------------
// value-path split-bf16 MFMA GEMM v2 (verified round 4): fused k-sweep +
// XCD-chunked swizzle.
// ---------------------------------------------------------------------------
__global__ __launch_bounds__(256) void mfma_gemm_split(
    const float* __restrict__ A, const ushort_t* __restrict__ WhiT,
    const ushort_t* __restrict__ WloT, const float* __restrict__ bias,
    float* __restrict__ C) {
  __shared__ ushort_t Ah[128 * 40];
  __shared__ ushort_t Al[128 * 40];
  __shared__ ushort_t Bh[128 * 40];
  __shared__ ushort_t Bl[128 * 40];
  int s = blockIdx.x;
  int o = (s & 7) * 128 + (s >> 3);  // nwg = 1024, cpx = 128
  int n0 = (o & 3) * 128, m0 = (o >> 2) * 128;
  int t = threadIdx.x;
  int lane = t & 63, w = t >> 6;
  int wm = w >> 1, wn = w & 1;
  int mrow = lane & 15, quad = lane >> 4;
  floatx4 acc[4][4] = {};
  for (int kp = 0; kp < 16; ++kp) {
    int k0 = kp * 32;
    __syncthreads();
#pragma unroll
    for (int p = 0; p < 2; ++p) {
      int idx = p * 256 + t;
      int r = idx >> 2, c = (idx & 3) * 8;
      const float* ap = A + (size_t)(m0 + r) * 512 + k0 + c;
      floatx4 f0 = *(const floatx4*)ap;
      floatx4 f1 = *(const floatx4*)(ap + 4);
      short8 vh, vl;
#pragma unroll
      for (int j = 0; j < 8; ++j) {
        float fv = (j < 4) ? f0[j] : f1[j - 4];
        ushort_t hb = f2bf(fv);
        vh[j] = (short)hb;
        vl[j] = (short)f2bf(fv - bf2f(hb));
      }
      *(short8*)&Ah[r * 40 + c] = vh;
      *(short8*)&Al[r * 40 + c] = vl;
      size_t boff = (size_t)(n0 + r) * 512 + k0 + c;
      *(short8*)&Bh[r * 40 + c] = *(const short8*)(WhiT + boff);
      *(short8*)&Bl[r * 40 + c] = *(const short8*)(WloT + boff);
    }
    __syncthreads();
    int abase = (wm * 64 + mrow) * 40 + quad * 8;
    int bbase = (wn * 64 + mrow) * 40 + quad * 8;
    short8 ah[4], bh[4];
#pragma unroll
    for (int i = 0; i < 4; ++i) {
      ah[i] = *(const short8*)&Ah[abase + i * 640];
      bh[i] = *(const short8*)&Bh[bbase + i * 640];
    }
#pragma unroll
    for (int mt = 0; mt < 4; ++mt)
#pragma unroll
      for (int nt = 0; nt < 4; ++nt)
        acc[mt][nt] = __builtin_amdgcn_mfma_f32_16x16x32_bf16(
            ah[mt], bh[nt], acc[mt][nt], 0, 0, 0);
    {
      short8 al[4];
#pragma unroll
      for (int i = 0; i < 4; ++i) al[i] = *(const short8*)&Al[abase + i * 640];
#pragma unroll
      for (int mt = 0; mt < 4; ++mt)
#pragma unroll
        for (int nt = 0; nt < 4; ++nt)
          acc[mt][nt] = __builtin_amdgcn_mfma_f32_16x16x32_bf16(
              al[mt], bh[nt], acc[mt][nt], 0, 0, 0);
    }
    {
      short8 bl[4];
#pragma unroll
      for (int i = 0; i < 4; ++i) bl[i] = *(const short8*)&Bl[bbase + i * 640];
#pragma unroll
      for (int mt = 0; mt < 4; ++mt)
#pragma unroll
        for (int nt = 0; nt < 4; ++nt)
          acc[mt][nt] = __builtin_amdgcn_mfma_f32_16x16x32_bf16(
              ah[mt], bl[nt], acc[mt][nt], 0, 0, 0);
    }
  }
#pragma unroll
  for (int nt = 0; nt < 4; ++nt) {
    int gn = n0 + wn * 64 + nt * 16 + mrow;
    float bb = bias[gn];
#pragma unroll
    for (int mt = 0; mt < 4; ++mt) {
      int gm = m0 + wm * 64 + mt * 16 + quad * 4;
#pragma unroll
      for (int rg = 0; rg < 4; ++rg)
        C[(size_t)(gm + rg) * 512 + gn] = acc[mt][nt][rg] + bb;
    }
  }
}

// ---------------------------------------------------------------------------
// attention v7 (verified round 7: 247us, VGPR 60, no spill): f32 qk, fp64
// score dot via cvt, f32-radix select + exact u64 refine, EPS=2e-6 ramp,
// 64KB LDS pool reuse, 2-deep PV prefetch. v8's 8-deep prefetch spilled
// (WRITE_SIZE 32->175MB) -- reverted.
// ---------------------------------------------------------------------------
__global__ __launch_bounds__(1024) void attn_kernel(
    const float* __restrict__ qk, const float* __restrict__ vbuf,
    const float* __restrict__ corr_prior, const float* __restrict__ feat_imp,
    const double* __restrict__ pv, float* __restrict__ attn_out, int b_off,
    int nb) {
  __shared__ __align__(16) float smem[16384];  // 64KB pool
  // phase A: kT = smem[0:8192) as [d=64][128 skewed]; q_w = smem[8192+w*512)
  // phase B (after barrier): p_w = smem[w*1024 .. +1024)
  int s = blockIdx.x;
  int o = (s & 7) * nb + (s >> 3);  // nwg = 8*nb
  int b = o >> 3, h = o & 7;  // chunk-local b
  int t = threadIdx.x, lane = t & 63, w = t >> 6;
#pragma unroll
  for (int n = 0; n < 8; ++n) {
    int f = w + 16 * n;
    smem[lane * 128 + ((f + lane) & 127)] =
        qk[((size_t)(b * F_ + f)) * 1024 + 512 + h * 64 + lane];
  }
  float* qpw = &smem[8192 + w * 512];
  int fb = 8 * w;  // this wave's 8-row group
#pragma unroll
  for (int i = 0; i < 8; ++i)
    qpw[i * 64 + lane] =
        qk[((size_t)(b * F_ + fb + i)) * 1024 + h * 64 + lane];
  __syncthreads();
  double pvb = pv[b_off + b] * 0.5;
  double fiA = (double)feat_imp[lane];
  double fiB = (double)feat_imp[64 + lane];
  const double SLOPE = 2.5e5;  // 1/(2*EPS), EPS = 2e-6
  double s0[8], s1[8];
#pragma unroll
  for (int i = 0; i < 8; ++i) {
    s0[i] = 0.0;
    s1[i] = 0.0;
  }
#pragma unroll 2
  for (int d = 0; d < 64; d += 2) {
    double kd0a = (double)smem[d * 128 + ((lane + d) & 127)];
    double kd1a = (double)smem[d * 128 + ((lane + 64 + d) & 127)];
    double kd0b = (double)smem[(d + 1) * 128 + ((lane + 1 + d) & 127)];
    double kd1b = (double)smem[(d + 1) * 128 + ((lane + 65 + d) & 127)];
#pragma unroll
    for (int i = 0; i < 8; ++i) {
      floatx2 q2 = *(const floatx2*)&qpw[i * 64 + d];
      double qa = (double)q2[0], qb = (double)q2[1];
      s0[i] += qa * kd0a;
      s1[i] += qa * kd1a;
      s0[i] += qb * kd0b;
      s1[i] += qb * kd1b;
    }
  }
  float p0s[8], p1s[8];
#pragma unroll
  for (int i = 0; i < 8; ++i) {
    int f = fb + i;
    double sa = s0[i], sb = s1[i];
    double fif = (double)feat_imp[f];
    double cp0 = (double)corr_prior[f * 128 + lane] * fif * fiA;
    double cp1 = (double)corr_prior[f * 128 + 64 + lane] * fif * fiB;
    double add0 = (f < 64) ? 0.0 : pvb;
    double add1 = (f < 64) ? pvb : 0.0;
    sa = sa * 0.125 + cp0 + add0;
    sb = sb * 0.125 + cp1 + add1;
    // stage 1: 32-round select on f32-ordered keys (monotone cast)
    unsigned a0 = f2ord32((float)sa), a1 = f2ord32((float)sb), T = 0u;
    for (int bit = 31; bit >= 0; --bit) {
      unsigned cand = T | (1u << bit);
      int c = __popcll(__ballot(a0 >= cand)) + __popcll(__ballot(a1 >= cand));
      if (c >= KVAL_) T = cand;
    }
    int cnt_gt = __popcll(__ballot(a0 > T)) + __popcll(__ballot(a1 > T));
    int cnt_ge = __popcll(__ballot(a0 >= T)) + __popcll(__ballot(a1 >= T));
    int bsz = cnt_ge - cnt_gt;
    int r = KVAL_ - cnt_gt;  // in-bucket kept count
    double bmax = -1e300;    // max strictly below bucket
    if (a0 < T) bmax = sa;
    if (a1 < T && sb > bmax) bmax = sb;
    for (int off = 32; off; off >>= 1) bmax = fmax(bmax, __shfl_xor(bmax, off));
    double sT, sU;
    if (bsz == r) {  // common: whole bucket kept
      double tmin = 1e300;
      if (a0 == T) tmin = sa;
      if (a1 == T && sb < tmin) tmin = sb;
      for (int off = 32; off; off >>= 1) tmin = fmin(tmin, __shfl_xor(tmin, off));
      sT = tmin;
      sU = bmax;
    } else {  // rare: exact u64 refine inside tied bucket
      unsigned long long x0 = (a0 == T) ? f2ord64(sa) : 0ull;
      unsigned long long x1 = (a1 == T) ? f2ord64(sb) : 0ull;
      unsigned long long T64 = 0ull;
      for (int bit = 63; bit >= 0; --bit) {
        unsigned long long cand = T64 | (1ull << bit);
        int c = __popcll(__ballot(x0 >= cand)) + __popcll(__ballot(x1 >= cand));
        if (c >= r) T64 = cand;
      }
      double tv = -1e300, uv = bmax;
      if (x0 == T64) tv = sa;
      if (x1 == T64 && sb > tv) tv = sb;
      if (a0 == T && x0 < T64 && sa > uv) uv = sa;
      if (a1 == T && x1 < T64 && sb > uv) uv = sb;
      for (int off = 32; off; off >>= 1) {
        tv = fmax(tv, __shfl_xor(tv, off));
        uv = fmax(uv, __shfl_xor(uv, off));
      }
      sT = tv;
      sU = uv;
    }
    double mid = 0.5 * (sT + sU);
    double W0 = fmin(1.0, fmax(0.0, 0.5 + (sa - mid) * SLOPE));
    double W1v = fmin(1.0, fmax(0.0, 0.5 + (sb - mid) * SLOPE));
    double mm = fmax(sa, sb);
    for (int off = 32; off; off >>= 1) mm = fmax(mm, __shfl_xor(mm, off));
    float p0 = (float)W0 * expf((float)(sa - mm));
    float p1 = (float)W1v * expf((float)(sb - mm));
    float zz = p0 + p1;
    for (int off = 32; off; off >>= 1) zz += __shfl_xor(zz, off);
    float inv = 1.f / zz;
    p0s[i] = p0 * inv;
    p1s[i] = p1 * inv;
  }
  // all QK reads of kT/q done across the block -> reuse pool for p
  __syncthreads();
  float* pp = &smem[w * 1024];
#pragma unroll
  for (int i = 0; i < 8; ++i) {
    pp[i * 128 + lane] = p0s[i];
    pp[i * 128 + 64 + lane] = p1s[i];
  }
  // PV: v loads shared across the 8 rows; j ascending = old col order
  const float* vb = vbuf + ((size_t)b * F_) * 512 + h * 64 + lane;
  float o8[8] = {0.f, 0.f, 0.f, 0.f, 0.f, 0.f, 0.f, 0.f};
  float vj0 = vb[0], vj1 = vb[512];
  for (int j = 0; j < 128; j += 2) {
    float va = vj0, vbb = vj1;
    if (j + 2 < 128) {
      vj0 = vb[(size_t)(j + 2) * 512];
      vj1 = vb[(size_t)(j + 3) * 512];
    }
#pragma unroll
    for (int i = 0; i < 8; ++i) {
      floatx2 p2 = *(const floatx2*)&pp[i * 128 + j];
      o8[i] += p2[0] * va;
      o8[i] += p2[1] * vbb;
    }
  }
#pragma unroll
  for (int i = 0; i < 8; ++i)
    attn_out[((size_t)(b * F_ + fb + i)) * 512 + h * 64 + lane] = o8[i];
}

extern "C" void kernel_launch(void* const* d_in, const int* in_sizes, int n_in,
                              void* d_out, int out_size, void* d_ws,
                              size_t ws_size, hipStream_t stream) {
  const float* x = (const float*)d_in[0];
  const float* Wq = (const float*)d_in[1];
  const float* bq = (const float*)d_in[2];
  const float* Wk = (const float*)d_in[3];
  const float* bk = (const float*)d_in[4];
  const float* Wv = (const float*)d_in[5];
  const float* bv = (const float*)d_in[6];
  const float* Wo = (const float*)d_in[7];
  const float* bo = (const float*)d_in[8];
  const float* corr = (const float*)d_in[9];
  const float* fimp = (const float*)d_in[10];
  const float* W1 = (const float*)d_in[11];
  const float* b1 = (const float*)d_in[12];
  const float* W2 = (const float*)d_in[13];
  const float* b2 = (const float*)d_in[14];
  float* out = (float*)d_out;
  float* ws = (float*)d_ws;

  // workspace layout (float units)
  double* pv_hi = (double*)ws;
  double* bqk_hi = (double*)(ws + 512);
  ushort_t* WqkTh = (ushort_t*)(ws + 2560);
  ushort_t* WqkTm = (ushort_t*)(ws + 264704);
  ushort_t* WqkTl = (ushort_t*)(ws + 526848);
  ushort_t* WvhiT = (ushort_t*)(ws + 788992);
  ushort_t* WvloT = (ushort_t*)(ws + 920064);
  ushort_t* WohiT = (ushort_t*)(ws + 1051136);
  ushort_t* WoloT = (ushort_t*)(ws + 1182208);
  float* vbuf = ws + 1313280;
  float* attnb = ws + 18090496;
  float* qk = ws + 34867712;  // f32
  const size_t head = 34867712;
  size_t ws_floats = ws_size / 4;
  // per-chunk per-b: qk 131072 floats + x 3-split 49152 floats
  int Bc = 8;
  for (int cand = 256; cand >= 8; cand >>= 1)
    if (head + (size_t)cand * 180224 <= ws_floats) { Bc = cand; break; }
  ushort_t* Xh = (ushort_t*)(ws + head + (size_t)Bc * 131072);
  ushort_t* Xm = Xh + (size_t)Bc * 65536;
  ushort_t* Xl = Xm + (size_t)Bc * 65536;

  hipLaunchKernelGGL(pv_kernel, dim3(B_), dim3(256), 0, stream,
                     x, W1, b1, W2, b2, pv_hi);
  hipLaunchKernelGGL(pack_wqk3_kernel, dim3(2048), dim3(256), 0, stream,
                     Wq, Wk, bq, bk, WqkTh, WqkTm, WqkTl, bqk_hi);
  hipLaunchKernelGGL(pack_wt_kernel, dim3(1024), dim3(256), 0, stream,
                     Wv, WvhiT, WvloT);
  hipLaunchKernelGGL(pack_wt_kernel, dim3(1024), dim3(256), 0, stream,
                     Wo, WohiT, WoloT);
  // v projection: full batch, M = 32768
  hipLaunchKernelGGL(mfma_gemm_split, dim3(1024), dim3(256), 0, stream,
                     x, WvhiT, WvloT, bv, vbuf);
  // selection path, chunked over batch
  for (int b0 = 0; b0 < B_; b0 += Bc) {
    hipLaunchKernelGGL(xsplit3_kernel, dim3(Bc * 32), dim3(256), 0, stream,
                       x + (size_t)b0 * 65536, Xh, Xm, Xl);
    hipLaunchKernelGGL(mfma_qk_v3, dim3(8 * Bc), dim3(256), 0, stream,
                       Xh, Xm, Xl, WqkTh, WqkTm, WqkTl, bqk_hi, qk, Bc);
    hipLaunchKernelGGL(attn_kernel, dim3(Bc * 8), dim3(1024), 0, stream,
                       qk, vbuf + (size_t)b0 * 65536, corr, fimp, pv_hi,
                       attnb + (size_t)b0 * 65536, b0, Bc);
  }
  // output projection: full batch
  hipLaunchKernelGGL(mfma_gemm_split, dim3(1024), dim3(256), 0, stream,
                     attnb, WohiT, WoloT, bo, out);
}